// Round 3
// baseline (1131.859 us; speedup 1.0000x reference)
//
#include <hip/hip_runtime.h>

// 3-layer tanh RNN as ONE persistent, layer-pipelined kernel.
// Block = one batch row = 3 waves (wave l handles layer l). At global step s,
// wave l computes its layer's timestep t = s - l. h vectors flow between
// layers through depth-2 LDS rings; one __syncthreads() per step.
//  - 12 waves/CU (3/SIMD) instead of round-2's 4/CU (1/SIMD): three
//    independent recurrence chains interleave on each SIMD -> latency hidden.
//  - No intermediate h-seq in HBM at all (round-2: 131 MB write + re-read).
//  - Weights (Wih,Whh rows for own layer) pinned in VGPRs; __launch_bounds__
//    (192,3) caps allocation so 3 waves/SIMD stay resident.

typedef __attribute__((ext_vector_type(2))) float f32x2;
typedef __attribute__((ext_vector_type(4))) float f32x4;

#define RNN_B 1024
#define RNN_T 512
#define RNN_H 64
#define RNN_L 3

static __device__ __forceinline__ f32x2 mk2(float a, float b) {
    f32x2 r; r.x = a; r.y = b; return r;
}

__global__ __launch_bounds__(192, 3)
void rnn_pipeline(const float* __restrict__ x,     // [B,T,H]
                  const float* __restrict__ Wih,   // [L,H,H]
                  const float* __restrict__ Whh,   // [L,H,H]
                  const float* __restrict__ bih,   // [L,H]
                  const float* __restrict__ bhh,   // [L,H]
                  const float* __restrict__ fcw,   // [H]
                  const float* __restrict__ fcb,   // [1]
                  float* __restrict__ out)         // [B]
{
    // ring[l] = layer l's h (producer wave l, consumer waves l and l+1),
    // ring[3] = x broadcast staging (wave 0 only). Slot parity = t & 1.
    __shared__ f32x4 ring[RNN_L + 1][2][RNN_H / 4];

    const int lane = threadIdx.x & 63;
    const int l    = threadIdx.x >> 6;      // wave id == layer id
    const int b    = blockIdx.x;            // batch row

    // ---- Own layer's weight rows into VGPRs (lane j holds row j) ----
    f32x2 wi[RNN_H / 2], wh[RNN_H / 2];
    {
        const f32x4* wr = (const f32x4*)(Wih + ((size_t)l * RNN_H + lane) * RNN_H);
        const f32x4* hr = (const f32x4*)(Whh + ((size_t)l * RNN_H + lane) * RNN_H);
#pragma unroll
        for (int c = 0; c < RNN_H / 4; ++c) {
            f32x4 a = wr[c];
            wi[2*c+0] = mk2(a.x, a.y); wi[2*c+1] = mk2(a.z, a.w);
            f32x4 d = hr[c];
            wh[2*c+0] = mk2(d.x, d.y); wh[2*c+1] = mk2(d.z, d.w);
        }
    }
#pragma unroll
    for (int i = 0; i < RNN_H / 2; ++i)
        asm volatile("" : "+v"(wi[i]), "+v"(wh[i]));   // pin: no re-loads in loop

    const float bias = bih[l * RNN_H + lane] + bhh[l * RNN_H + lane];
    const float fw   = fcw[lane];
    const float fb   = fcb[0];

    // Zero own h ring (both slots); t=0 reads slot (t-1)&1 == 1 -> must be 0.
    ((float*)&ring[l][0][0])[lane] = 0.0f;
    ((float*)&ring[l][1][0])[lane] = 0.0f;

    const float* xrow = x + (size_t)b * RNN_T * RNN_H;
    float xr = 0.0f, xn = 0.0f;
    if (l == 0) {
        ((float*)&ring[3][0][0])[lane] = xrow[lane];   // publish x_0
        xr = xrow[RNN_H + lane];                       // x_1 (publish at t=0)
        xn = xrow[2 * RNN_H + lane];                   // x_2
    }
    __syncthreads();

    const int in_ring = (l == 0) ? 3 : (l - 1);
    float hval = 0.0f;

    for (int s = 0; s < RNN_T + RNN_L - 1; ++s) {
        const int t = s - l;
        const bool active = (t >= 0) && (t < RNN_T);   // wave-uniform
        if (active) {
            const int si = t & 1;          // input slot (x_t or h^{l-1}_t)
            const int sh = (t - 1) & 1;    // own h_{t-1} slot

            f32x2 a0 = mk2(bias, 0.0f), a1 = mk2(0.f, 0.f);
            f32x2 a2 = mk2(0.f, 0.f),   a3 = mk2(0.f, 0.f);
#pragma unroll
            for (int c = 0; c < RNN_H / 4; ++c) {
                f32x4 v = ring[in_ring][si][c];        // 64-lane broadcast
                a0 += mk2(v.x, v.y) * wi[2*c+0];
                a1 += mk2(v.z, v.w) * wi[2*c+1];
            }
#pragma unroll
            for (int c = 0; c < RNN_H / 4; ++c) {
                f32x4 v = ring[l][sh][c];              // broadcast
                a2 += mk2(v.x, v.y) * wh[2*c+0];
                a3 += mk2(v.z, v.w) * wh[2*c+1];
            }
            const f32x2 ss = (a0 + a2) + (a1 + a3);
            const float pre = ss.x + ss.y;

            // tanh, overflow-safe (same formula as rounds 1-2, which passed)
            const float ax = fabsf(pre);
            const float e  = __expf(-2.0f * ax);
            const float r  = (1.0f - e) / (1.0f + e);
            hval = copysignf(r, pre);

            ((float*)&ring[l][t & 1][0])[lane] = hval;  // publish h_t

            if (l == 0) {
                if (t + 1 < RNN_T)
                    ((float*)&ring[3][(t + 1) & 1][0])[lane] = xr;  // publish x_{t+1}
                xr = xn;
                const int tn = (t + 3 < RNN_T) ? (t + 3) : (RNN_T - 1);
                xn = xrow[(size_t)tn * RNN_H + lane];    // prefetch 2 ahead
            }

            if (l == 2 && t == RNN_T - 1) {
                float p = hval * fw;                     // FC head, last step
#pragma unroll
                for (int off = 32; off > 0; off >>= 1)
                    p += __shfl_xor(p, off, 64);
                if (lane == 0) out[b] = p + fb;
            }
        }
        __syncthreads();
    }
}

extern "C" void kernel_launch(void* const* d_in, const int* in_sizes, int n_in,
                              void* d_out, int out_size, void* d_ws, size_t ws_size,
                              hipStream_t stream)
{
    const float* x   = (const float*)d_in[0];
    const float* Wih = (const float*)d_in[1];
    const float* Whh = (const float*)d_in[2];
    const float* bih = (const float*)d_in[3];
    const float* bhh = (const float*)d_in[4];
    const float* fcw = (const float*)d_in[5];
    const float* fcb = (const float*)d_in[6];
    float* out = (float*)d_out;                // [B,1]

    rnn_pipeline<<<dim3(RNN_B), dim3(RNN_L * 64), 0, stream>>>(
        x, Wih, Whh, bih, bhh, fcw, fcb, out);
}

// Round 4
// 1129.269 us; speedup vs baseline: 1.0023x; 1.0023x over previous
//
#include <hip/hip_runtime.h>

// 3-layer tanh RNN as ONE persistent, layer-pipelined kernel.
// Block = one batch row = 3 waves (wave l handles layer l). At global step s,
// wave l computes its layer's timestep t = s - l; h flows between layers
// through depth-2 LDS rings; one __syncthreads() per step.
//
// Round-4 fix vs round-3: ring values consumed INLINE (one f32x4 temp at a
// time, round-2's proven pattern). Round 3 hoisted 32 f32x4 ring reads into
// arrays = +128 floats of working set -> allocator spilled the 128 pinned
// weight regs to scratch under the (192,3) cap (VGPR_Count=84, 64 scratch
// reloads/step, 2x regression). Inline consumption keeps working set ~16.

typedef __attribute__((ext_vector_type(2))) float f32x2;
typedef __attribute__((ext_vector_type(4))) float f32x4;

#define RNN_B 1024
#define RNN_T 512
#define RNN_H 64
#define RNN_L 3

static __device__ __forceinline__ f32x2 mk2(float a, float b) {
    f32x2 r; r.x = a; r.y = b; return r;
}

__global__ __launch_bounds__(192, 3)
void rnn_pipeline(const float* __restrict__ x,     // [B,T,H]
                  const float* __restrict__ Wih,   // [L,H,H]
                  const float* __restrict__ Whh,   // [L,H,H]
                  const float* __restrict__ bih,   // [L,H]
                  const float* __restrict__ bhh,   // [L,H]
                  const float* __restrict__ fcw,   // [H]
                  const float* __restrict__ fcb,   // [1]
                  float* __restrict__ out)         // [B]
{
    // ring[l] = layer l's h (producer wave l, consumers l and l+1),
    // ring[3] = x broadcast staging (wave 0 only). Slot parity = t & 1.
    __shared__ f32x4 ring[RNN_L + 1][2][RNN_H / 4];

    const int lane = threadIdx.x & 63;
    const int l    = threadIdx.x >> 6;      // wave id == layer id
    const int b    = blockIdx.x;            // batch row

    // ---- Own layer's weight rows into VGPRs (lane j holds row j) ----
    f32x2 wi[RNN_H / 2], wh[RNN_H / 2];
    {
        const f32x4* wr = (const f32x4*)(Wih + ((size_t)l * RNN_H + lane) * RNN_H);
        const f32x4* hr = (const f32x4*)(Whh + ((size_t)l * RNN_H + lane) * RNN_H);
#pragma unroll
        for (int c = 0; c < RNN_H / 4; ++c) {
            f32x4 a = wr[c];
            wi[2*c+0] = mk2(a.x, a.y); wi[2*c+1] = mk2(a.z, a.w);
            f32x4 d = hr[c];
            wh[2*c+0] = mk2(d.x, d.y); wh[2*c+1] = mk2(d.z, d.w);
        }
    }
#pragma unroll
    for (int i = 0; i < RNN_H / 2; ++i)
        asm volatile("" : "+v"(wi[i]), "+v"(wh[i]));   // pin: no re-loads in loop

    const float bias = bih[l * RNN_H + lane] + bhh[l * RNN_H + lane];
    const float fw   = fcw[lane];
    const float fb   = fcb[0];

    // Zero own h ring (both slots); t=0 reads slot (t-1)&1 == 1 -> must be 0.
    ((float*)&ring[l][0][0])[lane] = 0.0f;
    ((float*)&ring[l][1][0])[lane] = 0.0f;

    const float* xrow = x + (size_t)b * RNN_T * RNN_H;
    float xr = 0.0f, xn = 0.0f;
    if (l == 0) {
        ((float*)&ring[3][0][0])[lane] = xrow[lane];   // publish x_0
        xr = xrow[RNN_H + lane];                       // x_1 (publish at t=0)
        xn = xrow[2 * RNN_H + lane];                   // x_2
    }
    __syncthreads();

    const int in_ring = (l == 0) ? 3 : (l - 1);
    float hval = 0.0f;

    for (int s = 0; s < RNN_T + RNN_L - 1; ++s) {
        const int t = s - l;
        const bool active = (t >= 0) && (t < RNN_T);   // wave-uniform
        if (active) {
            const int si = t & 1;          // input slot (x_t or h^{l-1}_t)
            const int sh = (t - 1) & 1;    // own h_{t-1} slot

            f32x2 a0 = mk2(bias, 0.0f), a1 = mk2(0.f, 0.f);
            f32x2 a2 = mk2(0.f, 0.f),   a3 = mk2(0.f, 0.f);
            // Inline consumption: one f32x4 broadcast temp at a time.
#pragma unroll
            for (int c = 0; c < RNN_H / 4; ++c) {
                f32x4 v = ring[in_ring][si][c];        // 64-lane broadcast
                a0 += mk2(v.x, v.y) * wi[2*c+0];
                a1 += mk2(v.z, v.w) * wi[2*c+1];
            }
#pragma unroll
            for (int c = 0; c < RNN_H / 4; ++c) {
                f32x4 v = ring[l][sh][c];              // broadcast
                a2 += mk2(v.x, v.y) * wh[2*c+0];
                a3 += mk2(v.z, v.w) * wh[2*c+1];
            }
            const f32x2 ss = (a0 + a2) + (a1 + a3);
            const float pre = ss.x + ss.y;

            // tanh, overflow-safe (same formula as rounds 1-3, all passed)
            const float ax = fabsf(pre);
            const float e  = __expf(-2.0f * ax);
            const float r  = (1.0f - e) / (1.0f + e);
            hval = copysignf(r, pre);

            ((float*)&ring[l][t & 1][0])[lane] = hval;  // publish h_t

            if (l == 0) {
                if (t + 1 < RNN_T)
                    ((float*)&ring[3][(t + 1) & 1][0])[lane] = xr;  // publish x_{t+1}
                xr = xn;
                const int tn = (t + 3 < RNN_T) ? (t + 3) : (RNN_T - 1);
                xn = xrow[(size_t)tn * RNN_H + lane];    // prefetch 2 ahead
            }

            if (l == 2 && t == RNN_T - 1) {
                float p = hval * fw;                     // FC head, last step
#pragma unroll
                for (int off = 32; off > 0; off >>= 1)
                    p += __shfl_xor(p, off, 64);
                if (lane == 0) out[b] = p + fb;
            }
        }
        __syncthreads();
    }
}

extern "C" void kernel_launch(void* const* d_in, const int* in_sizes, int n_in,
                              void* d_out, int out_size, void* d_ws, size_t ws_size,
                              hipStream_t stream)
{
    const float* x   = (const float*)d_in[0];
    const float* Wih = (const float*)d_in[1];
    const float* Whh = (const float*)d_in[2];
    const float* bih = (const float*)d_in[3];
    const float* bhh = (const float*)d_in[4];
    const float* fcw = (const float*)d_in[5];
    const float* fcb = (const float*)d_in[6];
    float* out = (float*)d_out;                // [B,1]

    rnn_pipeline<<<dim3(RNN_B), dim3(RNN_L * 64), 0, stream>>>(
        x, Wih, Whh, bih, bhh, fcw, fcb, out);
}

// Round 5
// 957.981 us; speedup vs baseline: 1.1815x; 1.1788x over previous
//
#include <hip/hip_runtime.h>

// 3-layer tanh RNN: persistent layer-pipelined kernel, 2 batch rows/block.
// Block = 3 waves (wave l = layer l); at global step s wave l computes
// timestep t = s - l for BOTH of the block's batch rows; h flows through
// depth-2 LDS rings; one __syncthreads() per step.
//
// Round-5 root-cause fix: VGPR_Count history {84,128,84,84} = gfx950
// occupancy tiers {6,4,6,6} waves/EU -> the scheduler voluntarily targets a
// high occupancy tier and spills the 128 loop-invariant weight regs to reach
// it (launch_bounds' 2nd arg is only a MIN). amdgpu_waves_per_eu(2,2) pins
// the target at 2 waves/EU -> 256-reg budget -> weights stay resident.
// 2 rows/wave matches supplied occupancy (grid 512 -> 2 blocks/CU) to that
// budget and doubles per-wave ILP (two independent recurrence chains).

typedef __attribute__((ext_vector_type(2))) float f32x2;
typedef __attribute__((ext_vector_type(4))) float f32x4;

#define RNN_B 1024
#define RNN_T 512
#define RNN_H 64
#define RNN_L 3
#define RPB   2   // batch rows per block

static __device__ __forceinline__ f32x2 mk2(float a, float b) {
    f32x2 r; r.x = a; r.y = b; return r;
}

__global__ __launch_bounds__(RNN_L * 64)
__attribute__((amdgpu_waves_per_eu(2, 2)))
void rnn_pipeline(const float* __restrict__ x,     // [B,T,H]
                  const float* __restrict__ Wih,   // [L,H,H]
                  const float* __restrict__ Whh,   // [L,H,H]
                  const float* __restrict__ bih,   // [L,H]
                  const float* __restrict__ bhh,   // [L,H]
                  const float* __restrict__ fcw,   // [H]
                  const float* __restrict__ fcb,   // [1]
                  float* __restrict__ out)         // [B]
{
    // ring[l][slot][row] = layer l's h; ring[3] = x staging (wave 0 writes).
    __shared__ f32x4 ring[RNN_L + 1][2][RPB][RNN_H / 4];

    const int lane = threadIdx.x & 63;
    const int l    = threadIdx.x >> 6;      // wave id == layer id
    const int b0   = blockIdx.x * RPB;

    // ---- Own layer's weight rows into VGPRs (lane j holds row j) ----
    f32x2 wi[RNN_H / 2], wh[RNN_H / 2];
    {
        const f32x4* wr = (const f32x4*)(Wih + ((size_t)l * RNN_H + lane) * RNN_H);
        const f32x4* hr = (const f32x4*)(Whh + ((size_t)l * RNN_H + lane) * RNN_H);
#pragma unroll
        for (int c = 0; c < RNN_H / 4; ++c) {
            f32x4 a = wr[c];
            wi[2*c+0] = mk2(a.x, a.y); wi[2*c+1] = mk2(a.z, a.w);
            f32x4 d = hr[c];
            wh[2*c+0] = mk2(d.x, d.y); wh[2*c+1] = mk2(d.z, d.w);
        }
    }
#pragma unroll
    for (int i = 0; i < RNN_H / 2; ++i)
        asm volatile("" : "+v"(wi[i]), "+v"(wh[i]));

    const float bias = bih[l * RNN_H + lane] + bhh[l * RNN_H + lane];
    const float fw   = fcw[lane];
    const float fb   = fcb[0];

    // Zero own h ring (both slots, both rows).
#pragma unroll
    for (int sl = 0; sl < 2; ++sl)
#pragma unroll
        for (int r = 0; r < RPB; ++r)
            ((float*)&ring[l][sl][r][0])[lane] = 0.0f;

    const float* xb = x + (size_t)b0 * RNN_T * RNN_H;  // rows b0, b0+1
    const size_t rowstride = (size_t)RNN_T * RNN_H;
    float xr0 = 0.f, xn0 = 0.f, xr1 = 0.f, xn1 = 0.f;
    if (l == 0) {
        ((float*)&ring[3][0][0][0])[lane] = xb[lane];              // x_0 row0
        ((float*)&ring[3][0][1][0])[lane] = xb[rowstride + lane];  // x_0 row1
        xr0 = xb[RNN_H + lane];                 xn0 = xb[2 * RNN_H + lane];
        xr1 = xb[rowstride + RNN_H + lane];     xn1 = xb[rowstride + 2 * RNN_H + lane];
    }
    __syncthreads();

    const int in_ring = (l == 0) ? 3 : (l - 1);
    float hv0 = 0.0f, hv1 = 0.0f;

    for (int s = 0; s < RNN_T + RNN_L - 1; ++s) {
        const int t = s - l;
        const bool active = (t >= 0) && (t < RNN_T);   // wave-uniform
        if (active) {
            const int si = t & 1;          // input slot (x_t or h^{l-1}_t)
            const int sh = (t - 1) & 1;    // own h_{t-1} slot

            f32x2 a00 = mk2(bias, 0.f), a01 = mk2(0.f, 0.f);
            f32x2 a02 = mk2(0.f, 0.f),  a03 = mk2(0.f, 0.f);
            f32x2 a10 = mk2(bias, 0.f), a11 = mk2(0.f, 0.f);
            f32x2 a12 = mk2(0.f, 0.f),  a13 = mk2(0.f, 0.f);

#pragma unroll
            for (int c = 0; c < RNN_H / 4; ++c) {
                f32x4 v0 = ring[in_ring][si][0][c];    // broadcast row0 input
                f32x4 v1 = ring[in_ring][si][1][c];    // broadcast row1 input
                a00 += mk2(v0.x, v0.y) * wi[2*c+0];
                a01 += mk2(v0.z, v0.w) * wi[2*c+1];
                a10 += mk2(v1.x, v1.y) * wi[2*c+0];
                a11 += mk2(v1.z, v1.w) * wi[2*c+1];
            }
#pragma unroll
            for (int c = 0; c < RNN_H / 4; ++c) {
                f32x4 u0 = ring[l][sh][0][c];          // broadcast row0 h
                f32x4 u1 = ring[l][sh][1][c];          // broadcast row1 h
                a02 += mk2(u0.x, u0.y) * wh[2*c+0];
                a03 += mk2(u0.z, u0.w) * wh[2*c+1];
                a12 += mk2(u1.x, u1.y) * wh[2*c+0];
                a13 += mk2(u1.z, u1.w) * wh[2*c+1];
            }
            const f32x2 s0 = (a00 + a02) + (a01 + a03);
            const f32x2 s1 = (a10 + a12) + (a11 + a13);
            const float pre0 = s0.x + s0.y;
            const float pre1 = s1.x + s1.y;

            // tanh, overflow-safe (same formula as rounds 1-4, all passed)
            const float ax0 = fabsf(pre0);
            const float e0  = __expf(-2.0f * ax0);
            hv0 = copysignf((1.0f - e0) / (1.0f + e0), pre0);
            const float ax1 = fabsf(pre1);
            const float e1  = __expf(-2.0f * ax1);
            hv1 = copysignf((1.0f - e1) / (1.0f + e1), pre1);

            ((float*)&ring[l][t & 1][0][0])[lane] = hv0;  // publish h_t
            ((float*)&ring[l][t & 1][1][0])[lane] = hv1;

            if (l == 0) {
                if (t + 1 < RNN_T) {
                    ((float*)&ring[3][(t + 1) & 1][0][0])[lane] = xr0;
                    ((float*)&ring[3][(t + 1) & 1][1][0])[lane] = xr1;
                }
                xr0 = xn0; xr1 = xn1;
                const int tn = (t + 3 < RNN_T) ? (t + 3) : (RNN_T - 1);
                xn0 = xb[(size_t)tn * RNN_H + lane];               // prefetch
                xn1 = xb[rowstride + (size_t)tn * RNN_H + lane];
            }

            if (l == 2 && t == RNN_T - 1) {
                float p0 = hv0 * fw, p1 = hv1 * fw;    // FC head, last step
#pragma unroll
                for (int off = 32; off > 0; off >>= 1) {
                    p0 += __shfl_xor(p0, off, 64);
                    p1 += __shfl_xor(p1, off, 64);
                }
                if (lane == 0) {
                    out[b0 + 0] = p0 + fb;
                    out[b0 + 1] = p1 + fb;
                }
            }
        }
        __syncthreads();
    }
}

extern "C" void kernel_launch(void* const* d_in, const int* in_sizes, int n_in,
                              void* d_out, int out_size, void* d_ws, size_t ws_size,
                              hipStream_t stream)
{
    const float* x   = (const float*)d_in[0];
    const float* Wih = (const float*)d_in[1];
    const float* Whh = (const float*)d_in[2];
    const float* bih = (const float*)d_in[3];
    const float* bhh = (const float*)d_in[4];
    const float* fcw = (const float*)d_in[5];
    const float* fcb = (const float*)d_in[6];
    float* out = (float*)d_out;                // [B,1]

    rnn_pipeline<<<dim3(RNN_B / RPB), dim3(RNN_L * 64), 0, stream>>>(
        x, Wih, Whh, bih, bhh, fcw, fcb, out);
}